// Round 7
// baseline (67.571 us; speedup 1.0000x reference)
//
#include <hip/hip_runtime.h>

#define NTOK 16384   // B*T = 4*4096
#define BQ 4
#define TQ 4096
#define SQ 8192
#define BLK 1024
#define NBLK 16

typedef unsigned long long u64;

__device__ __forceinline__ unsigned score_key(float s) {
    unsigned u = __float_as_uint(s);
    if ((u << 1) == 0u) u = 0u;                 // -0.0 == +0.0
    return (u & 0x80000000u) ? ~u : (u | 0x80000000u);
}

// Every block redundantly computes the exact top-K threshold over packed
// P = (key << 14) | (16383 - idx)  (all distinct -> no tie-break), then writes
// its own 1/16 output slice. Zero inter-block synchronization.
// Level 0: 256 bins x 64 lane-private slots -> conflict-free LDS atomics.
__global__ __launch_bounds__(BLK) void token_update_kernel(
    const float* __restrict__ scores,
    const int* __restrict__ cand,
    const int* __restrict__ tok,
    const int* __restrict__ bids,
    const int* __restrict__ kptr,
    int* __restrict__ out0,
    int* __restrict__ out1)
{
    __shared__ int h0[256 * 64];      // 64 KB: level-0, slot = lane (conflict-free)
    __shared__ int hp[2][2048];       // 16 KB: ping-pong refinement hists
    __shared__ int cnt[256];
    __shared__ int wtot[16], wsuf[16];
    __shared__ u64 s_pref;
    __shared__ int s_krem, s_E;

    const int tid  = threadIdx.x;
    const int B    = blockIdx.x;
    const int lane = tid & 63;
    const int w    = tid >> 6;

    // ---- hoisted global loads: keys + epilogue slices + bids copy ----
    const float4* s4 = (const float4*)scores;
    float4 f[4];
    #pragma unroll
    for (int c = 0; c < 4; ++c) f[c] = s4[c * BLK + tid];

    float4 ef; int4 ec, et;
    if (tid < 256) {
        ef = s4[B * 256 + tid];
        ec = ((const int4*)cand)[B * 256 + tid];
        et = ((const int4*)tok)[B * 256 + tid];
    }
    if (tid < 512) {
        int g   = B * 512 + tid;              // [0, 8192) int4 units
        int o4  = g << 2;
        int c   = o4 >> 12;                   // chunk 0..7 (4096 ints)
        int b   = c & 3, plane = c >> 2;
        int off = o4 & 4095;
        int addr = plane ? (BQ * SQ + b * SQ + TQ + off) : (b * SQ + off);
        *(int4*)(out1 + addr) = *(const int4*)(bids + addr);
    }
    const int K = kptr[0];
    const bool none = (K <= 0), all = (K >= NTOK);
    const bool run  = !none && !all;          // uniform across block

    // ---- zero LDS (overlaps in-flight global loads) ----
    #pragma unroll
    for (int r = 0; r < 4; ++r)
        *(int4*)&h0[(r * BLK + tid) * 4] = make_int4(0, 0, 0, 0);
    *(int4*)&(((int*)hp)[tid * 4]) = make_int4(0, 0, 0, 0);
    if (tid == 0) { s_pref = 0ull; s_krem = 1; s_E = 1; }
    __syncthreads();

    // ---- level-0 histogram: conflict-free (lane-private slots) ----
    unsigned key[16];
    #pragma unroll
    for (int c = 0; c < 4; ++c) {
        key[c * 4 + 0] = score_key(f[c].x);
        key[c * 4 + 1] = score_key(f[c].y);
        key[c * 4 + 2] = score_key(f[c].z);
        key[c * 4 + 3] = score_key(f[c].w);
    }
    #pragma unroll
    for (int j = 0; j < 16; ++j)
        atomicAdd(&h0[(key[j] >> 24) * 64 + lane], 1);
    __syncthreads();

    // ---- reduce 64 slots -> cnt[256] (bin-rotated reads: <=2 lanes/bank) ----
    {
        int bin = tid >> 2, q = tid & 3;
        int base = bin * 64 + q * 16;
        int sum = 0;
        #pragma unroll
        for (int m = 0; m < 16; ++m)
            sum += h0[base + ((m + bin) & 15)];
        sum += __shfl_xor(sum, 1, 64);
        sum += __shfl_xor(sum, 2, 64);
        if (q == 0) cnt[bin] = sum;
    }
    __syncthreads();

    u64 pref = 0ull;
    int rb = 38;

    if (run) {
        // ---- level-0 scan: wave 0 alone, 4 bins/lane, shuffle suffix ----
        if (tid < 64) {
            int4 c = *(int4*)&cnt[tid * 4];
            int T = c.x + c.y + c.z + c.w;
            int incl = T;
            #pragma unroll
            for (int off = 1; off < 64; off <<= 1) {
                int o = __shfl_down(incl, off, 64);
                if (tid + off < 64) incl += o;
            }
            int s3 = incl - T,  n3 = s3 + c.w;
            int s2 = n3,        n2 = s2 + c.z;
            int s1 = n2,        n1 = s1 + c.y;
            int s0 = n1,        n0 = s0 + c.x;
            if (n3 >= K && s3 < K) { s_pref = (u64)(4 * tid + 3); s_krem = K - s3; s_E = c.w; }
            if (n2 >= K && s2 < K) { s_pref = (u64)(4 * tid + 2); s_krem = K - s2; s_E = c.z; }
            if (n1 >= K && s1 < K) { s_pref = (u64)(4 * tid + 1); s_krem = K - s1; s_E = c.y; }
            if (n0 >= K && s0 < K) { s_pref = (u64)(4 * tid + 0); s_krem = K - s0; s_E = c.x; }
        }
        __syncthreads();
        pref = s_pref;
        int krem = s_krem, E = s_E;

        // ---- refinement: 11,11,11,5 bits over P = (key<<14)|(16383-idx) ----
        const int SH[4] = {27, 16, 5, 0};
        for (int L = 0; L < 4 && krem != E; ++L) {
            const int sh = SH[L];
            const int bits = (L == 3) ? 5 : 11;
            int* hc = hp[L & 1];
            int* ho = hp[(L + 1) & 1];
            #pragma unroll
            for (int j = 0; j < 16; ++j) {
                int i = (((j >> 2) * BLK + tid) << 2) | (j & 3);
                u64 P = ((u64)key[j] << 14) | (unsigned)(NTOK - 1 - i);
                if ((P >> (sh + bits)) == pref)
                    atomicAdd(&hc[(int)((P >> sh) & ((1 << bits) - 1))], 1);
            }
            __syncthreads();

            if (bits == 11) {
                // block-wide suffix scan over 2048 bins; zero other buffer en route
                int c0 = hc[2 * tid], c1 = hc[2 * tid + 1];
                ho[2 * tid] = 0; ho[2 * tid + 1] = 0;
                int pairSum = c0 + c1, incl = pairSum;
                #pragma unroll
                for (int off = 1; off < 64; off <<= 1) {
                    int o = __shfl_down(incl, off, 64);
                    if (lane + off < 64) incl += o;
                }
                if (lane == 0) wtot[w] = incl;
                __syncthreads();
                if (tid < 16) {
                    int v = wtot[tid], i2 = v;
                    #pragma unroll
                    for (int off = 1; off < 16; off <<= 1) {
                        int o = __shfl_down(i2, off, 64);
                        if (tid + off < 16) i2 += o;
                    }
                    wsuf[tid] = i2 - v;
                }
                __syncthreads();
                int sufPair = (incl - pairSum) + wsuf[w];
                int suf1 = sufPair, n1 = suf1 + c1;
                int suf0 = n1,      n0 = suf0 + c0;
                if (n1 >= krem && suf1 < krem) {
                    s_pref = (pref << 11) | (unsigned)(2 * tid + 1);
                    s_krem = krem - suf1; s_E = c1;
                }
                if (n0 >= krem && suf0 < krem) {
                    s_pref = (pref << 11) | (unsigned)(2 * tid);
                    s_krem = krem - suf0; s_E = c0;
                }
                __syncthreads();
            } else {
                // final 5-bit level: wave 0 alone over 32 bins
                if (tid < 64) {
                    int c = (tid < 32) ? hc[tid] : 0;
                    int incl = c;
                    #pragma unroll
                    for (int off = 1; off < 64; off <<= 1) {
                        int o = __shfl_down(incl, off, 64);
                        if (tid + off < 64) incl += o;
                    }
                    int suf = incl - c;
                    if (tid < 32 && incl >= krem && suf < krem) {
                        s_pref = (pref << 5) | (unsigned)tid;
                        s_krem = krem - suf; s_E = c;
                    }
                }
                __syncthreads();
            }
            pref = s_pref; krem = s_krem; E = s_E; rb = sh;
        }
    }

    const u64 Tstar = none ? ~0ull : (all ? 0ull : (pref << rb));

    // ---- epilogue: preloaded slice -> out0 + both out1 windows ----
    if (tid < 256) {
        int i4 = B * 256 + tid;
        int i  = i4 << 2;
        u64 P0 = ((u64)score_key(ef.x) << 14) | (unsigned)(NTOK - 1 - (i + 0));
        u64 P1 = ((u64)score_key(ef.y) << 14) | (unsigned)(NTOK - 1 - (i + 1));
        u64 P2 = ((u64)score_key(ef.z) << 14) | (unsigned)(NTOK - 1 - (i + 2));
        u64 P3 = ((u64)score_key(ef.w) << 14) | (unsigned)(NTOK - 1 - (i + 3));
        int4 v;
        v.x = (P0 >= Tstar) ? ec.x : et.x;
        v.y = (P1 >= Tstar) ? ec.y : et.y;
        v.z = (P2 >= Tstar) ? ec.z : et.z;
        v.w = (P3 >= Tstar) ? ec.w : et.w;
        ((int4*)out0)[i4] = v;
        int b = i >> 12, tt = i & 4095;
        *(int4*)(out1 + b * SQ + (SQ - TQ) + tt) = v;   // plane 0 window
        *(int4*)(out1 + BQ * SQ + b * SQ + tt) = v;     // plane 1 window
    }
}

extern "C" void kernel_launch(void* const* d_in, const int* in_sizes, int n_in,
                              void* d_out, int out_size, void* d_ws, size_t ws_size,
                              hipStream_t stream) {
    const int*   tok    = (const int*)d_in[0];   // tokens          [4,4096]
    const int*   bids   = (const int*)d_in[1];   // batch_input_ids [2,4,8192]
    const int*   cand   = (const int*)d_in[2];   // candidate_tokens[4,4096]
    const float* scores = (const float*)d_in[3]; // candidate_scores[4,4096]
    const int*   kptr   = (const int*)d_in[4];   // unmask_count scalar

    int* out0 = (int*)d_out;        // updated_tokens, 16384 ints
    int* out1 = out0 + NTOK;        // upd, 65536 ints

    token_update_kernel<<<NBLK, BLK, 0, stream>>>(
        scores, cand, tok, bids, kptr, out0, out1);
}

// Round 8
// 65.409 us; speedup vs baseline: 1.0331x; 1.0331x over previous
//
#include <hip/hip_runtime.h>

#define NTOK 16384   // B*T = 4*4096
#define BQ 4
#define TQ 4096
#define SQ 8192
#define BLK 1024
#define NBLK 16

typedef unsigned long long u64;

__device__ __forceinline__ unsigned score_key(float s) {
    unsigned u = __float_as_uint(s);
    if ((u << 1) == 0u) u = 0u;                 // -0.0 == +0.0
    return (u & 0x80000000u) ? ~u : (u | 0x80000000u);
}

// Every block redundantly computes the exact top-K threshold over packed
// P = (key << 14) | (16383 - idx)  (all distinct -> no tie-break), then writes
// its own 1/16 output slice. Zero inter-block synchronization.
// All histogram levels use 1024 bins (10 bits): one bin per thread, uniform
// barrier-light suffix scan; h1 zeroing is folded into the count read.
__global__ __launch_bounds__(BLK) void token_update_kernel(
    const float* __restrict__ scores,
    const int* __restrict__ cand,
    const int* __restrict__ tok,
    const int* __restrict__ bids,
    const int* __restrict__ kptr,
    int* __restrict__ out0,
    int* __restrict__ out1)
{
    __shared__ int h0[1024 * 8];      // 32 KB: level-0, 8 slots/bin
    __shared__ int h1[1024];          // 4 KB: refinement hist
    __shared__ int wtot[16], wsuf[16];
    __shared__ u64 s_pref;
    __shared__ int s_krem, s_E;

    const int tid  = threadIdx.x;
    const int B    = blockIdx.x;
    const int lane = tid & 63;
    const int w    = tid >> 6;

    // ---- bids non-window copy (independent; issue first to overlap) ----
    if (tid < 512) {
        int g   = B * 512 + tid;              // [0, 8192) int4 units
        int o4  = g << 2;
        int c   = o4 >> 12;                   // chunk 0..7 (4096 ints)
        int b   = c & 3, plane = c >> 2;
        int off = o4 & 4095;
        int addr = plane ? (BQ * SQ + b * SQ + TQ + off) : (b * SQ + off);
        *(int4*)(out1 + addr) = *(const int4*)(bids + addr);
    }

    const int K = kptr[0];
    const bool none = (K <= 0), all = (K >= NTOK);
    const bool run  = !none && !all;          // uniform across block

    // ---- zero LDS ----
    *(int4*)&h0[tid * 8]     = make_int4(0, 0, 0, 0);
    *(int4*)&h0[tid * 8 + 4] = make_int4(0, 0, 0, 0);
    h1[tid] = 0;
    if (tid == 0) { s_pref = 0ull; s_krem = 1; s_E = 1; }
    __syncthreads();

    // ---- load ALL 16384 keys (16/thread, float4 coalesced) ----
    unsigned key[16];
    const float4* s4 = (const float4*)scores;
    #pragma unroll
    for (int c = 0; c < 4; ++c) {
        float4 f = s4[c * BLK + tid];
        key[c * 4 + 0] = score_key(f.x);
        key[c * 4 + 1] = score_key(f.y);
        key[c * 4 + 2] = score_key(f.z);
        key[c * 4 + 3] = score_key(f.w);
    }

    u64 pref = 0ull;
    int rb = 36;

    if (run) {
        // ---- level-0 histogram: top 10 key bits, 8 slots ----
        const int slot = tid & 7;
        #pragma unroll
        for (int j = 0; j < 16; ++j)
            atomicAdd(&h0[(key[j] >> 22) * 8 + slot], 1);
        __syncthreads();

        // P-domain shifts: P = (key << 14) | (16383 - idx), 46 bits total.
        const int SH[5]   = {36, 26, 16, 6, 0};
        const int BITS[5] = {10, 10, 10, 10, 6};
        int krem = K, E = 0;

        for (int L = 0; L < 5; ++L) {
            // my bin's count; fold h1 zeroing into the read (same address)
            int c;
            if (L == 0) {
                int4 a = *(int4*)&h0[tid * 8];
                int4 b = *(int4*)&h0[tid * 8 + 4];
                c = a.x + a.y + a.z + a.w + b.x + b.y + b.z + b.w;
            } else {
                c = h1[tid];
                h1[tid] = 0;
            }
            // block-wide suffix scan over 1024 bins (1 bin/thread)
            int incl = c;
            #pragma unroll
            for (int off = 1; off < 64; off <<= 1) {
                int o = __shfl_down(incl, off, 64);
                if (lane + off < 64) incl += o;
            }
            if (lane == 0) wtot[w] = incl;
            __syncthreads();
            if (tid < 16) {
                int v = wtot[tid], i2 = v;
                #pragma unroll
                for (int off = 1; off < 16; off <<= 1) {
                    int o = __shfl_down(i2, off, 64);
                    if (tid + off < 16) i2 += o;
                }
                wsuf[tid] = i2 - v;            // sum of waves strictly after
            }
            __syncthreads();
            int suf = (incl - c) + wsuf[w];    // elements strictly above my bin
            int n   = suf + c;
            if ((L > 0 || tid < 1024) && n >= krem && suf < krem) {
                s_pref = (pref << BITS[L]) | (unsigned)tid;
                s_krem = krem - suf; s_E = c;
            }
            __syncthreads();
            pref = s_pref; krem = s_krem; E = s_E; rb = SH[L];
            if (krem == E || L == 4) break;    // boundary bin fully selected

            // next-level histogram over boundary-bin survivors
            const int nsh = SH[L + 1], nbits = BITS[L + 1];
            #pragma unroll
            for (int j = 0; j < 16; ++j) {
                int i = (((j >> 2) * BLK + tid) << 2) | (j & 3);
                u64 P = ((u64)key[j] << 14) | (unsigned)(NTOK - 1 - i);
                if ((P >> (nsh + nbits)) == pref)
                    atomicAdd(&h1[(int)((P >> nsh) & ((1 << nbits) - 1))], 1);
            }
            __syncthreads();
        }
    }

    const u64 Tstar = none ? ~0ull : (all ? 0ull : (pref << rb));

    // ---- output: block B writes its 1/16 slice of out0 + both out1 windows ----
    if (tid < 256) {
        int i4 = B * 256 + tid;                // [0, 4096) int4 units
        int i  = i4 << 2;
        float4 f = s4[i4];                     // L2-hot reload
        int4 c4 = ((const int4*)cand)[i4];
        int4 t4 = ((const int4*)tok)[i4];
        u64 P0 = ((u64)score_key(f.x) << 14) | (unsigned)(NTOK - 1 - (i + 0));
        u64 P1 = ((u64)score_key(f.y) << 14) | (unsigned)(NTOK - 1 - (i + 1));
        u64 P2 = ((u64)score_key(f.z) << 14) | (unsigned)(NTOK - 1 - (i + 2));
        u64 P3 = ((u64)score_key(f.w) << 14) | (unsigned)(NTOK - 1 - (i + 3));
        int4 v;
        v.x = (P0 >= Tstar) ? c4.x : t4.x;
        v.y = (P1 >= Tstar) ? c4.y : t4.y;
        v.z = (P2 >= Tstar) ? c4.z : t4.z;
        v.w = (P3 >= Tstar) ? c4.w : t4.w;
        ((int4*)out0)[i4] = v;
        int b = i >> 12, tt = i & 4095;
        *(int4*)(out1 + b * SQ + (SQ - TQ) + tt) = v;   // plane 0 window
        *(int4*)(out1 + BQ * SQ + b * SQ + tt) = v;     // plane 1 window
    }
}

extern "C" void kernel_launch(void* const* d_in, const int* in_sizes, int n_in,
                              void* d_out, int out_size, void* d_ws, size_t ws_size,
                              hipStream_t stream) {
    const int*   tok    = (const int*)d_in[0];   // tokens          [4,4096]
    const int*   bids   = (const int*)d_in[1];   // batch_input_ids [2,4,8192]
    const int*   cand   = (const int*)d_in[2];   // candidate_tokens[4,4096]
    const float* scores = (const float*)d_in[3]; // candidate_scores[4,4096]
    const int*   kptr   = (const int*)d_in[4];   // unmask_count scalar

    int* out0 = (int*)d_out;        // updated_tokens, 16384 ints
    int* out1 = out0 + NTOK;        // upd, 65536 ints

    token_update_kernel<<<NBLK, BLK, 0, stream>>>(
        scores, cand, tok, bids, kptr, out0, out1);
}